// Round 1
// baseline (2344.078 us; speedup 1.0000x reference)
//
#include <hip/hip_runtime.h>
#include <cstdint>

#define NQ 16
#define NDEPTH 4
#define NBATCH 512

// ---------------------------------------------------------------------------
// Compile-time GF(2) tracking of the CNOT ring.
// Physical index x (16 bits): bit b corresponds to wire (15-b).
// Invariant: logical basis index y = A x (bits). Rotation on logical wire q:
//   pair mask  Delta = A^{-1} e_p   (p = 15-q, physical-bit mask)
//   parity row R     = row_p(A)     (logical bit value = parity(x & R))
// CNOT(c,t): Arow[pt] ^= Arow[pc]; Ainv_col[pc] ^= Ainv_col[pt].
// ---------------------------------------------------------------------------
struct Masks {
  unsigned short delta[NDEPTH][NQ];
  unsigned short rowm[NDEPTH][NQ];
  unsigned short meas[NQ];
};

constexpr Masks make_masks() {
  Masks m = {};
  unsigned short Arow[NQ] = {};
  unsigned short Ainv[NQ] = {};
  for (int p = 0; p < NQ; ++p) {
    Arow[p] = (unsigned short)(1u << p);
    Ainv[p] = (unsigned short)(1u << p);
  }
  for (int d = 0; d < NDEPTH; ++d) {
    for (int q = 0; q < NQ; ++q) {        // rotations of this layer use current A
      m.delta[d][q] = Ainv[15 - q];
      m.rowm[d][q]  = Arow[15 - q];
    }
    for (int q = 0; q < NQ - 1; ++q) {    // CNOT(q, q+1)
      const int pc = 15 - q, pt = 15 - (q + 1);
      Arow[pt] = (unsigned short)(Arow[pt] ^ Arow[pc]);
      Ainv[pc] = (unsigned short)(Ainv[pc] ^ Ainv[pt]);
    }
    {                                      // CNOT(15, 0)
      const int pc = 15 - 15, pt = 15 - 0;
      Arow[pt] = (unsigned short)(Arow[pt] ^ Arow[pc]);
      Ainv[pc] = (unsigned short)(Ainv[pc] ^ Ainv[pt]);
    }
  }
  for (int q = 0; q < NQ; ++q) m.meas[q] = Arow[15 - q];
  return m;
}

constexpr Masks MK = make_masks();

__device__ __forceinline__ float2 cmul(float2 a, float2 b) {
  return make_float2(a.x * b.x - a.y * b.y, a.x * b.y + a.y * b.x);
}
// acc + a*b
__device__ __forceinline__ float2 cfma(float2 a, float2 b, float2 acc) {
  return make_float2(fmaf(a.x, b.x, fmaf(-a.y, b.y, acc.x)),
                     fmaf(a.x, b.y, fmaf(a.y, b.x, acc.y)));
}

// ---------------------------------------------------------------------------
// One rotation gate. All masks constexpr -> every s[] index is static.
// Layout: x = (tid << 6) | r ;  tid[5:0]=lane, tid[9:6]=wave, r = register.
// ---------------------------------------------------------------------------
template<int D, int Q>
__device__ __forceinline__ void apply_gate(float2* s, float2* xch,
                                           const float2* utab, int tid) {
  constexpr int DLT  = MK.delta[D][Q];
  constexpr int R    = MK.rowm[D][Q];
  constexpr int dreg = DLT & 63;
  constexpr int dthr = (DLT >> 6) & 1023;

  const int gbase = (D * NQ + Q) * 4;
  const float2 U00 = utab[gbase + 0];
  const float2 U01 = utab[gbase + 1];
  const float2 U10 = utab[gbase + 2];
  const float2 U11 = utab[gbase + 3];
  const int pt = __popc((tid << 6) & R) & 1;  // parity contribution of thread bits

  if constexpr (dthr == 0) {
    // ---- Case A: both pair elements in my own registers ----
    constexpr int LB = dreg & (-dreg);
#pragma unroll
    for (int r = 0; r < 64; ++r) {
      if (r & LB) continue;               // folded at compile time
      const int r2 = r ^ dreg;
      const float2 a = s[r], c = s[r2];
      const int bb = pt ^ (__popc(r & R) & 1);  // parity of element at r
      // lo = amplitude with logical bit 0, hi = with bit 1
      const float2 lo = bb ? c : a;
      const float2 hi = bb ? a : c;
      const float2 nlo = cfma(U00, lo, cmul(U01, hi));
      const float2 nhi = cfma(U10, lo, cmul(U11, hi));
      s[r]  = bb ? nhi : nlo;
      s[r2] = bb ? nlo : nhi;
    }
  } else if constexpr ((dthr >> 6) == 0) {
    // ---- Case B: partner in another lane of the same wave (shuffle) ----
    constexpr int dlane = dthr;
    if constexpr (dreg == 0) {
#pragma unroll
      for (int r = 0; r < 64; ++r) {
        const float2 m = s[r];
        float2 p;
        p.x = __shfl_xor(m.x, dlane);
        p.y = __shfl_xor(m.y, dlane);
        const int bb = pt ^ (__popc(r & R) & 1);
        const float2 ca = bb ? U11 : U00;
        const float2 cb = bb ? U10 : U01;
        s[r] = cfma(ca, m, cmul(cb, p));
      }
    } else {
      constexpr int LB = dreg & (-dreg);
#pragma unroll
      for (int r = 0; r < 64; ++r) {
        if (r & LB) continue;
        const int r2 = r ^ dreg;
        const float2 m0 = s[r], m1 = s[r2];
        float2 p0, p1;
        p0.x = __shfl_xor(m1.x, dlane);   // partner lane's old s[r^dreg]
        p0.y = __shfl_xor(m1.y, dlane);
        p1.x = __shfl_xor(m0.x, dlane);   // partner lane's old s[r]
        p1.y = __shfl_xor(m0.y, dlane);
        const int b0 = pt ^ (__popc(r & R) & 1);
        const int b1 = pt ^ (__popc(r2 & R) & 1);
        const float2 ca0 = b0 ? U11 : U00, cb0 = b0 ? U10 : U01;
        const float2 ca1 = b1 ? U11 : U00, cb1 = b1 ? U10 : U01;
        s[r]  = cfma(ca0, m0, cmul(cb0, p0));
        s[r2] = cfma(ca1, m1, cmul(cb1, p1));
      }
    }
  } else {
    // ---- Case C: partner in another thread (possibly other wave) via LDS ----
    const int pthr = tid ^ dthr;
    if constexpr ((dreg >> 3) == 0) {
      // partner reg lives in the same 8-register chunk
#pragma unroll
      for (int k = 0; k < 8; ++k) {
#pragma unroll
        for (int j = 0; j < 8; ++j) xch[j * 1024 + tid] = s[k * 8 + j];
        __syncthreads();
#pragma unroll
        for (int j = 0; j < 8; ++j) {
          const int r = k * 8 + j;
          const float2 m = s[r];
          const float2 p = xch[(j ^ dreg) * 1024 + pthr];
          const int bb = pt ^ (__popc(r & R) & 1);
          const float2 ca = bb ? U11 : U00;
          const float2 cb = bb ? U10 : U01;
          s[r] = cfma(ca, m, cmul(cb, p));
        }
        __syncthreads();
      }
    } else {
      // partner reg in a different chunk: process chunk pairs (4-reg chunks)
      constexpr int kx = dreg >> 2;       // >= 2 here
#pragma unroll
      for (int c = 0; c < 16; ++c) {
        if (c > (c ^ kx)) continue;       // each unordered pair once (folded)
        const int c2 = c ^ kx;
#pragma unroll
        for (int j = 0; j < 4; ++j) {
          xch[j * 1024 + tid]       = s[c * 4 + j];
          xch[(4 + j) * 1024 + tid] = s[c2 * 4 + j];
        }
        __syncthreads();
#pragma unroll
        for (int j = 0; j < 4; ++j) {
          {
            const int r = c * 4 + j;      // partner is in chunk c2 -> slots 4..7
            const float2 m = s[r];
            const float2 p = xch[(4 + ((r ^ dreg) & 3)) * 1024 + pthr];
            const int bb = pt ^ (__popc(r & R) & 1);
            const float2 ca = bb ? U11 : U00;
            const float2 cb = bb ? U10 : U01;
            s[r] = cfma(ca, m, cmul(cb, p));
          }
          {
            const int r = c2 * 4 + j;     // partner is in chunk c -> slots 0..3
            const float2 m = s[r];
            const float2 p = xch[((r ^ dreg) & 3) * 1024 + pthr];
            const int bb = pt ^ (__popc(r & R) & 1);
            const float2 ca = bb ? U11 : U00;
            const float2 cb = bb ? U10 : U01;
            s[r] = cfma(ca, m, cmul(cb, p));
          }
        }
        __syncthreads();
      }
    }
  }
}

template<int D, int Q>
__device__ __forceinline__ void apply_all(float2* s, float2* xch,
                                          const float2* utab, int tid) {
  apply_gate<D, Q>(s, xch, utab, tid);
  if constexpr (Q < NQ - 1) {
    apply_all<D, Q + 1>(s, xch, utab, tid);
  } else if constexpr (D < NDEPTH - 1) {
    apply_all<D + 1, 0>(s, xch, utab, tid);
  }
}

__global__ __launch_bounds__(1024) void qsim_kernel(const float* __restrict__ x,
                                                    const float* __restrict__ params,
                                                    float* __restrict__ out) {
  __shared__ float2 xch[8192];                 // 64 KB exchange buffer
  __shared__ float2 utab[NDEPTH * NQ * 4];     // 2 KB gate matrices

  const int tid = threadIdx.x;
  const int b = blockIdx.x;

  // ---- per-block gate table: U = RZ(tz) RY(ty) RX(tx) ----
  if (tid < NDEPTH * NQ) {
    const int d = tid / NQ, q = tid % NQ;
    const float a = tanhf(x[b * NQ + q]);
    const float tx = a + params[(d * NQ + q) * 3 + 0];
    const float ty = a + params[(d * NQ + q) * 3 + 1];
    const float tz = a + params[(d * NQ + q) * 3 + 2];
    const float cx = cosf(0.5f * tx), sx = sinf(0.5f * tx);
    const float cy = cosf(0.5f * ty), sy = sinf(0.5f * ty);
    const float cz = cosf(0.5f * tz), sz = sinf(0.5f * tz);
    // RY*RX entries
    const float2 m00 = make_float2(cy * cx,  sy * sx);
    const float2 m01 = make_float2(-sy * cx, -cy * sx);
    const float2 m10 = make_float2(sy * cx,  -cy * sx);
    const float2 m11 = make_float2(cy * cx,  -sy * sx);
    const float2 ez  = make_float2(cz, -sz);   // e^{-i tz/2}
    const float2 ezc = make_float2(cz,  sz);
    utab[tid * 4 + 0] = cmul(ez,  m00);
    utab[tid * 4 + 1] = cmul(ez,  m01);
    utab[tid * 4 + 2] = cmul(ezc, m10);
    utab[tid * 4 + 3] = cmul(ezc, m11);
  }

  // ---- state init: |0..0> ----
  float2 s[64];
#pragma unroll
  for (int r = 0; r < 64; ++r) s[r] = make_float2(0.f, 0.f);
  if (tid == 0) s[0].x = 1.0f;
  __syncthreads();

  // ---- all 64 rotation gates (CNOTs folded into the constexpr masks) ----
  apply_all<0, 0>(s, xch, utab, tid);

  // ---- Z expectations: z_q = sum_x (-1)^{parity(x & meas_q)} |s[x]|^2 ----
  float z[NQ];
#pragma unroll
  for (int q = 0; q < NQ; ++q) z[q] = 0.f;
  float sgn[NQ];
#pragma unroll
  for (int q = 0; q < NQ; ++q)
    sgn[q] = (__popc((tid << 6) & MK.meas[q]) & 1) ? -1.f : 1.f;
#pragma unroll
  for (int r = 0; r < 64; ++r) {
    const float pr = s[r].x * s[r].x + s[r].y * s[r].y;
#pragma unroll
    for (int q = 0; q < NQ; ++q) {
      const bool neg = (__popc(r & MK.meas[q]) & 1) != 0;  // constexpr-folded
      z[q] = fmaf(neg ? -sgn[q] : sgn[q], pr, z[q]);
    }
  }
  // wave-level butterfly reduce
#pragma unroll
  for (int q = 0; q < NQ; ++q) {
    float v = z[q];
#pragma unroll
    for (int mk = 32; mk >= 1; mk >>= 1) v += __shfl_xor(v, mk);
    z[q] = v;
  }
  __syncthreads();                 // xch free for reuse
  float* red = (float*)xch;
  if ((tid & 63) == 0) {
    const int w = tid >> 6;
#pragma unroll
    for (int q = 0; q < NQ; ++q) red[w * NQ + q] = z[q];
  }
  __syncthreads();
  if (tid < NQ) {
    float acc = 0.f;
#pragma unroll
    for (int w = 0; w < 16; ++w) acc += red[w * NQ + tid];
    out[b * NQ + tid] = acc;
  }
}

extern "C" void kernel_launch(void* const* d_in, const int* in_sizes, int n_in,
                              void* d_out, int out_size, void* d_ws, size_t ws_size,
                              hipStream_t stream) {
  const float* x      = (const float*)d_in[0];
  const float* params = (const float*)d_in[1];
  float* out          = (float*)d_out;
  qsim_kernel<<<dim3(NBATCH), dim3(1024), 0, stream>>>(x, params, out);
}